// Round 12
// baseline (87.583 us; speedup 1.0000x reference)
//
#include <hip/hip_runtime.h>
#include <math.h>

#define SELU_SCALE 1.0507009873554805f
#define SELU_ALPHA 1.6732632423543772f

constexpr int CIN  = 3;
constexpr int HH   = 32;
constexpr int WW   = 32;
constexpr int OUTF = 64;

typedef _Float16 f16x8 __attribute__((ext_vector_type(8)));
typedef float    f32x4 __attribute__((ext_vector_type(4)));

__device__ __forceinline__ unsigned int pack2(float a, float b) {
    return __builtin_bit_cast(unsigned int, __builtin_amdgcn_cvt_pkrtz(a, b));
}

template <int CTRL, int ROW_MASK>
__device__ __forceinline__ float dpp_add(float v) {
    int sh = __builtin_amdgcn_update_dpp(0, __float_as_int(v),
                                         CTRL, ROW_MASK, 0xf, false);
    return v + __int_as_float(sh);
}
__device__ __forceinline__ float wave64_sum(float v) {
    v = dpp_add<0x111, 0xf>(v);
    v = dpp_add<0x112, 0xf>(v);
    v = dpp_add<0x114, 0xf>(v);
    v = dpp_add<0x118, 0xf>(v);
    v = dpp_add<0x142, 0xa>(v);  // row_bcast:15
    v = dpp_add<0x143, 0xc>(v);  // row_bcast:31
    return v;
}

__device__ __forceinline__ float selu_ns(float s) {  // SELU without outer scale
    const float e = fmaf(__expf(s), SELU_ALPHA, -SELU_ALPHA);
    return s > 0.f ? s : e;
}

// One block per image; 4 waves x 16 position-tiles; implicit-GEMM
// mfma_f32_16x16x32_f16 (A = patches, B = weights w/ k>=27 rows zero,
// C = bias broadcast). C layout: col=lane&15 -> oc, row=quad*4+i -> position;
// LPPool pairs are intra-lane. 1-stage software pipeline: MFMAs of tile jt
// issue before the SELU/sqrt epilogue of tile jt-1 (round 11, +1.2us).
// Round-12: occupancy 4 -> 6 blocks/CU (__launch_bounds__(256,6), caps VGPR
// at 84) — the clean TLP test round-10's split conflated with overhead.
__global__ __launch_bounds__(256, 6) void fused_conv_mfma(
    const float* __restrict__ x,            // (1024, 3, 32, 32)
    const float* __restrict__ weight,       // (27, 64)
    const float* __restrict__ bias,         // (64,)
    const float* __restrict__ scale_proj,   // (3, 64)
    const float* __restrict__ scale_bias,   // (64,)
    float* __restrict__ out)                // (1024, 64)
{
    const int n    = blockIdx.x;
    const int t    = threadIdx.x;
    const int lane = t & 63;
    const int wv   = t >> 6;
    const int quad = lane >> 4;
    const int m16  = lane & 15;

    __shared__ float xs[CIN][34][34];   // zero-padded input tile, 13.9 KB
    __shared__ uint4 wfrag[4][64];      // packed B fragments, 4 KB
    __shared__ float red4[4][4][OUTF];  // per-(wave,quad) pooled partials, 4 KB
    __shared__ float credu[CIN][4];

    // ---- zero the padded tile + pack B fragments (one barrier) ----
    float* xsf = &xs[0][0][0];
    for (int i = t; i < CIN * 34 * 34; i += 256) xsf[i] = 0.f;
    {
        const int ot = t >> 6, ln = t & 63;
        const int oc = ot * 16 + (ln & 15);
        const int k0 = (ln >> 4) * 8;
        unsigned int d[4];
        #pragma unroll
        for (int r = 0; r < 4; ++r) {
            const int ka = k0 + 2 * r, kb = ka + 1;
            const float wa = (ka < 27) ? weight[ka * OUTF + oc] : 0.f;
            const float wb = (kb < 27) ? weight[kb * OUTF + oc] : 0.f;
            d[r] = pack2(wa, wb);
        }
        wfrag[ot][ln] = make_uint4(d[0], d[1], d[2], d[3]);
    }
    __syncthreads();

    // ---- load x[n] into LDS interior + per-channel sums ----
    const float* xn = x + (size_t)n * (CIN * HH * WW);
    float cp0 = 0.f, cp1 = 0.f, cp2 = 0.f;
    for (int i = t; i < CIN * HH * WW; i += 256) {
        float v  = xn[i];
        int   c  = i >> 10;
        int   hw = i & 1023;
        xs[c][(hw >> 5) + 1][(hw & 31) + 1] = v;
        if (c == 0) cp0 += v; else if (c == 1) cp1 += v; else cp2 += v;
    }
    cp0 = wave64_sum(cp0);
    cp1 = wave64_sum(cp1);
    cp2 = wave64_sum(cp2);
    if (lane == 63) { credu[0][wv] = cp0; credu[1][wv] = cp1; credu[2][wv] = cp2; }
    __syncthreads();

    // ---- B fragments + bias C operand ----
    f16x8 bfr[4];
    f32x4 cb[4];
    #pragma unroll
    for (int ot = 0; ot < 4; ++ot) {
        bfr[ot] = __builtin_bit_cast(f16x8, wfrag[ot][lane]);
        const float b = bias[ot * 16 + m16];
        cb[ot] = (f32x4){b, b, b, b};
    }

    // ---- per-lane tap offsets (k>=27: any valid addr — weight is 0) ----
    int loff[8];
    #pragma unroll
    for (int j = 0; j < 8; ++j) {
        const int k  = quad * 8 + j;
        const int c  = (k >= 18) ? 2 : (k >= 9 ? 1 : 0);
        const int rm = k - 9 * c;
        const int rr = (rm >= 6) ? 2 : (rm >= 3 ? 1 : 0);
        const int cc = rm - 3 * rr;
        loff[j] = (k < 27) ? (c * 1156 + rr * 34 + cc + m16) : m16;
    }

    // ---- pipelined main loop: MFMA(jt) before epilogue(jt-1) ----
    float racc[4] = {0.f, 0.f, 0.f, 0.f};
    const int tile0 = wv * 16;

    auto load_mfma = [&](int jt, f32x4* dst) {
        const int tile  = tile0 + jt;
        const int sbase = (tile >> 1) * 34 + (tile & 1) * 16;
        float v[8];
        #pragma unroll
        for (int j = 0; j < 8; ++j) v[j] = xsf[sbase + loff[j]];
        const uint4 au = make_uint4(pack2(v[0], v[1]), pack2(v[2], v[3]),
                                    pack2(v[4], v[5]), pack2(v[6], v[7]));
        const f16x8 af = __builtin_bit_cast(f16x8, au);
        #pragma unroll
        for (int ot = 0; ot < 4; ++ot)
            dst[ot] = __builtin_amdgcn_mfma_f32_16x16x32_f16(af, bfr[ot], cb[ot], 0, 0, 0);
    };
    auto epilogue = [&](const f32x4* dd) {
        #pragma unroll
        for (int ot = 0; ot < 4; ++ot) {
            const float s0 = selu_ns(dd[ot][0]);
            const float s1 = selu_ns(dd[ot][1]);
            const float s2 = selu_ns(dd[ot][2]);
            const float s3 = selu_ns(dd[ot][3]);
            racc[ot] += __builtin_amdgcn_sqrtf(fmaf(s0, s0, s1 * s1))
                      + __builtin_amdgcn_sqrtf(fmaf(s2, s2, s3 * s3));
        }
    };

    f32x4 dd[4];
    load_mfma(0, dd);
    #pragma unroll 2
    for (int jt = 1; jt < 16; ++jt) {
        f32x4 nd[4];
        load_mfma(jt, nd);      // in flight while we run the previous epilogue
        epilogue(dd);
        #pragma unroll
        for (int ot = 0; ot < 4; ++ot) dd[ot] = nd[ot];
    }
    epilogue(dd);

    // ---- stash per-(wave,quad) partials ----
    #pragma unroll
    for (int ot = 0; ot < 4; ++ot)
        red4[wv][quad][ot * 16 + m16] = racc[ot];
    __syncthreads();

    // ---- gate + store ----
    if (t < OUTF) {
        float s = 0.f;
        #pragma unroll
        for (int w = 0; w < 4; ++w)
            #pragma unroll
            for (int q = 0; q < 4; ++q)
                s += red4[w][q][t];
        const float mean = s * (SELU_SCALE / 512.f);   // 32*16 pooled elems
        float g = scale_bias[t];
        #pragma unroll
        for (int c = 0; c < CIN; ++c) {
            const float cs = (credu[c][0] + credu[c][1] + credu[c][2] + credu[c][3])
                             * (1.f / 1024.f);
            g = fmaf(cs, scale_proj[c * OUTF + t], g);
        }
        g = 1.f / (1.f + __expf(-g));
        out[(size_t)n * OUTF + t] = mean * g;
    }
}

extern "C" void kernel_launch(void* const* d_in, const int* in_sizes, int n_in,
                              void* d_out, int out_size, void* d_ws, size_t ws_size,
                              hipStream_t stream) {
    const float* x          = (const float*)d_in[0];
    const float* weight     = (const float*)d_in[1];
    const float* bias       = (const float*)d_in[2];
    const float* scale_proj = (const float*)d_in[3];
    const float* scale_bias = (const float*)d_in[4];
    float* out = (float*)d_out;

    fused_conv_mfma<<<1024, 256, 0, stream>>>(x, weight, bias,
                                              scale_proj, scale_bias, out);
}